// Round 2
// baseline (5564.720 us; speedup 1.0000x reference)
//
#include <hip/hip_runtime.h>
#include <hip/hip_bf16.h>

// GCN 2-hop SGConv: h = (D^-1/2 (A+I) D^-1/2)^2 x ; out = h @ W + b
// N=100000 nodes, E=1600000 edges, D=128.
// Runtime dtype detection (flags in ws):
//   flags[0] = 1 if x/W/b are f32 storage, 0 if bf16 storage
//   flags[1] = 1 if edge_index is int64 storage, 0 if int32
// h (f32 accum) lives in ws (51.2MB); hop-1 intermediate round-trips as bf16
// through d_out (fits under both output dtype scenarios). Total ws ~52MB.

#define DFEAT 128

typedef __attribute__((ext_vector_type(8))) short short8;
typedef __attribute__((ext_vector_type(4))) float f32x4;

__device__ __forceinline__ float bf2f(unsigned short u) {
    union { unsigned int i; float f; } t;
    t.i = ((unsigned int)u) << 16;
    return t.f;
}

__device__ __forceinline__ unsigned short f2bf(float f) {
    union { float f; unsigned int i; } t;
    t.f = f;
    unsigned int lsb = (t.i >> 16) & 1u;
    t.i += 0x7fffu + lsb;   // round-to-nearest-even
    return (unsigned short)(t.i >> 16);
}

__device__ __forceinline__ int esrc(const int* ei, int e, int i64) {
    return i64 ? ei[2 * e] : ei[e];
}
__device__ __forceinline__ int edst(const int* ei, int e, int E, int i64) {
    return i64 ? ei[2 * (E + e)] : ei[E + e];
}

// ---- dtype detection ----
__global__ void k_detect(const unsigned short* __restrict__ xs,
                         const int* __restrict__ ei, int* __restrict__ flags) {
    __shared__ int s_f32, s_oddnz;
    if (threadIdx.x == 0) { s_f32 = 0; s_oddnz = 0; }
    __syncthreads();
    int bad = 0;
    for (int i = threadIdx.x; i < 16384; i += 256) {
        unsigned int e = (xs[i] >> 7) & 0xFFu;   // bf16 exponent field
        if (e >= 0xC0u) bad = 1;                 // |v| >= 2^65: impossible for real bf16 data
    }
    if (bad) atomicOr(&s_f32, 1);
    int oddnz = 0;
    for (int i = threadIdx.x; i < 4096; i += 256) {
        if (ei[2 * i + 1] != 0) oddnz = 1;       // int32 data has nonzero odd words
    }
    if (oddnz) atomicOr(&s_oddnz, 1);
    __syncthreads();
    if (threadIdx.x == 0) {
        flags[0] = s_f32;
        flags[1] = s_oddnz ? 0 : 1;
    }
}

// ---- degree over dst (+1 self-loop applied in dinv) ----
__global__ void k_deg(const int* __restrict__ ei, int E, const int* __restrict__ flags,
                      int* __restrict__ degi) {
    int e = blockIdx.x * 256 + threadIdx.x;
    if (e >= E) return;
    atomicAdd(degi + edst(ei, e, E, flags[1]), 1);
}

__global__ void k_dinv(const int* __restrict__ degi, float* __restrict__ dinv, int n) {
    int i = blockIdx.x * 256 + threadIdx.x;
    if (i < n) dinv[i] = rsqrtf((float)(degi[i] + 1));
}

// ---- hop1 self-loop init: h[i] = x[i] * dinv[i]^2 (fully overwrites h) ----
__global__ void k_init1(const void* __restrict__ xraw, const float* __restrict__ dinv,
                        const int* __restrict__ flags, float* __restrict__ h, int n) {
    int gid = blockIdx.x * 256 + threadIdx.x;
    int node = gid >> 5;
    if (node >= n) return;
    int f = (gid & 31) << 2;
    float s = dinv[node]; s *= s;
    float4 v;
    if (flags[0]) {
        v = *(const float4*)((const float*)xraw + (size_t)node * DFEAT + f);
    } else {
        uint2 u = *(const uint2*)((const unsigned short*)xraw + (size_t)node * DFEAT + f);
        v.x = bf2f((unsigned short)(u.x & 0xffffu));
        v.y = bf2f((unsigned short)(u.x >> 16));
        v.z = bf2f((unsigned short)(u.y & 0xffffu));
        v.w = bf2f((unsigned short)(u.y >> 16));
    }
    v.x *= s; v.y *= s; v.z *= s; v.w *= s;
    *(float4*)(h + (size_t)node * DFEAT + f) = v;
}

// ---- hop1 edge scatter: h[dst] += x[src] * dinv[src]*dinv[dst] ----
__global__ void k_scat1(const void* __restrict__ xraw, const int* __restrict__ ei, int E,
                        const float* __restrict__ dinv, const int* __restrict__ flags,
                        float* __restrict__ h) {
    int gid = blockIdx.x * 256 + threadIdx.x;
    int e = gid >> 5;
    if (e >= E) return;
    int f = (gid & 31) << 2;
    int i64 = flags[1];
    int s = esrc(ei, e, i64);
    int d = edst(ei, e, E, i64);
    float w = dinv[s] * dinv[d];
    float4 v;
    if (flags[0]) {
        v = *(const float4*)((const float*)xraw + (size_t)s * DFEAT + f);
    } else {
        uint2 u = *(const uint2*)((const unsigned short*)xraw + (size_t)s * DFEAT + f);
        v.x = bf2f((unsigned short)(u.x & 0xffffu));
        v.y = bf2f((unsigned short)(u.x >> 16));
        v.z = bf2f((unsigned short)(u.y & 0xffffu));
        v.w = bf2f((unsigned short)(u.y >> 16));
    }
    float* hp = h + (size_t)d * DFEAT + f;
    atomicAdd(hp + 0, v.x * w);
    atomicAdd(hp + 1, v.y * w);
    atomicAdd(hp + 2, v.z * w);
    atomicAdd(hp + 3, v.w * w);
}

// ---- h (f32) -> hb (bf16, stored in d_out) ----
__global__ void k_tobf(const float* __restrict__ h, unsigned short* __restrict__ hb, int total4) {
    int i = blockIdx.x * 256 + threadIdx.x;
    if (i >= total4) return;
    float4 v = *(const float4*)(h + (size_t)i * 4);
    unsigned int lo = (unsigned int)f2bf(v.x) | ((unsigned int)f2bf(v.y) << 16);
    unsigned int hi = (unsigned int)f2bf(v.z) | ((unsigned int)f2bf(v.w) << 16);
    uint2 u; u.x = lo; u.y = hi;
    *(uint2*)(hb + (size_t)i * 4) = u;
}

// ---- hop2 self-loop init from bf16 hb ----
__global__ void k_init2(const unsigned short* __restrict__ hb, const float* __restrict__ dinv,
                        float* __restrict__ h, int n) {
    int gid = blockIdx.x * 256 + threadIdx.x;
    int node = gid >> 5;
    if (node >= n) return;
    int f = (gid & 31) << 2;
    float s = dinv[node]; s *= s;
    uint2 u = *(const uint2*)(hb + (size_t)node * DFEAT + f);
    float4 o;
    o.x = bf2f((unsigned short)(u.x & 0xffffu)) * s;
    o.y = bf2f((unsigned short)(u.x >> 16)) * s;
    o.z = bf2f((unsigned short)(u.y & 0xffffu)) * s;
    o.w = bf2f((unsigned short)(u.y >> 16)) * s;
    *(float4*)(h + (size_t)node * DFEAT + f) = o;
}

// ---- hop2 edge scatter from bf16 hb ----
__global__ void k_scat2(const unsigned short* __restrict__ hb, const int* __restrict__ ei, int E,
                        const float* __restrict__ dinv, const int* __restrict__ flags,
                        float* __restrict__ h) {
    int gid = blockIdx.x * 256 + threadIdx.x;
    int e = gid >> 5;
    if (e >= E) return;
    int f = (gid & 31) << 2;
    int i64 = flags[1];
    int s = esrc(ei, e, i64);
    int d = edst(ei, e, E, i64);
    float w = dinv[s] * dinv[d];
    uint2 u = *(const uint2*)(hb + (size_t)s * DFEAT + f);
    float* hp = h + (size_t)d * DFEAT + f;
    atomicAdd(hp + 0, bf2f((unsigned short)(u.x & 0xffffu)) * w);
    atomicAdd(hp + 1, bf2f((unsigned short)(u.x >> 16)) * w);
    atomicAdd(hp + 2, bf2f((unsigned short)(u.y & 0xffffu)) * w);
    atomicAdd(hp + 3, bf2f((unsigned short)(u.y >> 16)) * w);
}

// ---- W -> MFMA B-frag linear layout (bf16) ----
// frag (ntile, chunk): lane holds B[k = chunk*32 + (lane>>4)*8 + j][n = ntile*16 + (lane&15)]
__global__ void k_prepB(const void* __restrict__ Wraw, const int* __restrict__ flags,
                        unsigned short* __restrict__ Bf) {
    int t = blockIdx.x * 256 + threadIdx.x;  // 2048 total
    if (t >= 2048) return;
    int lane = t & 63;
    int chunk = (t >> 6) & 3;
    int ntile = t >> 8;
    int ncol = ntile * 16 + (lane & 15);
    int k0 = chunk * 32 + (lane >> 4) * 8;
    int isf = flags[0];
    const float* Wf = (const float*)Wraw;
    const unsigned short* Wb = (const unsigned short*)Wraw;
    unsigned short* o = Bf + (size_t)t * 8;
#pragma unroll
    for (int j = 0; j < 8; j++) {
        int idx = (k0 + j) * DFEAT + ncol;
        o[j] = isf ? f2bf(Wf[idx]) : Wb[idx];
    }
}

// ---- GEMM: out = h @ W + b, bf16 MFMA 16x16x32, one wave per 16-row tile ----
__global__ __launch_bounds__(256) void k_gemm(const float* __restrict__ h,
                                              const unsigned short* __restrict__ Bf,
                                              const void* __restrict__ braw,
                                              const int* __restrict__ flags,
                                              void* __restrict__ outraw, int n) {
    int wave = threadIdx.x >> 6;
    int lane = threadIdx.x & 63;
    int m0 = (blockIdx.x * 4 + wave) * 16;
    if (m0 >= n) return;
    int m = lane & 15, quad = lane >> 4;
    int isf = flags[0];
    const float* arow = h + (size_t)(m0 + m) * DFEAT + quad * 8;

    f32x4 acc[8];
#pragma unroll
    for (int nt = 0; nt < 8; nt++) acc[nt] = (f32x4){0.f, 0.f, 0.f, 0.f};

#pragma unroll
    for (int c = 0; c < 4; c++) {
        float4 a0 = *(const float4*)(arow + c * 32);
        float4 a1 = *(const float4*)(arow + c * 32 + 4);
        short8 af;
        af[0] = (short)f2bf(a0.x); af[1] = (short)f2bf(a0.y);
        af[2] = (short)f2bf(a0.z); af[3] = (short)f2bf(a0.w);
        af[4] = (short)f2bf(a1.x); af[5] = (short)f2bf(a1.y);
        af[6] = (short)f2bf(a1.z); af[7] = (short)f2bf(a1.w);
        const unsigned short* bp = Bf + ((size_t)c * 64 + lane) * 8;
#pragma unroll
        for (int nt = 0; nt < 8; nt++) {
            short8 bfr = *(const short8*)(bp + (size_t)nt * 2048);
            acc[nt] = __builtin_amdgcn_mfma_f32_16x16x32_bf16(af, bfr, acc[nt], 0, 0, 0);
        }
    }

    // C/D layout: col = lane&15, row = quad*4 + reg  [learn_hip m89/m91]
    int row0 = quad * 4;
    const float* bf32 = (const float*)braw;
    const unsigned short* bb16 = (const unsigned short*)braw;
    float* outf = (float*)outraw;
    unsigned short* outb = (unsigned short*)outraw;
#pragma unroll
    for (int nt = 0; nt < 8; nt++) {
        int col = nt * 16 + m;
        float bias = isf ? bf32[col] : bf2f(bb16[col]);
#pragma unroll
        for (int r = 0; r < 4; r++) {
            size_t idx = (size_t)(m0 + row0 + r) * DFEAT + col;
            float val = acc[nt][r] + bias;
            if (isf) outf[idx] = val; else outb[idx] = f2bf(val);
        }
    }
}

extern "C" void kernel_launch(void* const* d_in, const int* in_sizes, int n_in,
                              void* d_out, int out_size, void* d_ws, size_t ws_size,
                              hipStream_t stream) {
    const void* x = d_in[0];                 // [n,128] f32 or bf16 (detected)
    const int* ei = (const int*)d_in[1];     // [2,E] int32 or int64 (detected)
    const void* W = d_in[2];                 // [128,128]
    const void* b = d_in[3];                 // [128]

    const int n = in_sizes[0] / DFEAT;       // 100000
    const int E = in_sizes[1] / 2;           // 1600000

    // ws layout: h (n*128 f32) | dinv (n f32) | degi (n i32) | flags (4 i32) | Bf (16384 bf16)
    float* h = (float*)d_ws;
    float* dinv = h + (size_t)n * DFEAT;
    int* degi = (int*)(dinv + n);
    int* flags = degi + n;
    unsigned short* Bf = (unsigned short*)(flags + 4);
    unsigned short* hb = (unsigned short*)d_out;   // bf16 intermediate in d_out

    hipMemsetAsync(degi, 0, (size_t)(n + 4) * sizeof(int), stream);

    k_detect<<<1, 256, 0, stream>>>((const unsigned short*)x, ei, flags);
    k_deg<<<(E + 255) / 256, 256, 0, stream>>>(ei, E, flags, degi);
    k_dinv<<<(n + 255) / 256, 256, 0, stream>>>(degi, dinv, n);

    int feat_blocks_n = (n * 32 + 255) / 256;
    int feat_blocks_e = (int)(((long long)E * 32 + 255) / 256);

    // hop 1 into h
    k_init1<<<feat_blocks_n, 256, 0, stream>>>(x, dinv, flags, h, n);
    k_scat1<<<feat_blocks_e, 256, 0, stream>>>(x, ei, E, dinv, flags, h);

    // h -> bf16 hb (in d_out)
    k_tobf<<<(n * 32 + 255) / 256, 256, 0, stream>>>(h, hb, n * 32);

    // hop 2 into h (reads hb only)
    k_init2<<<feat_blocks_n, 256, 0, stream>>>(hb, dinv, h, n);
    k_scat2<<<feat_blocks_e, 256, 0, stream>>>(hb, ei, E, dinv, flags, h);

    // out = h @ W + b
    k_prepB<<<8, 256, 0, stream>>>(W, flags, Bf);
    int mtiles = (n + 15) / 16;                     // 6250
    k_gemm<<<(mtiles + 3) / 4, 256, 0, stream>>>(h, Bf, b, flags, d_out, n);
}

// Round 3
// 651.168 us; speedup vs baseline: 8.5457x; 8.5457x over previous
//
#include <hip/hip_runtime.h>
#include <hip/hip_bf16.h>

// GCN 2-hop SGConv via CSR gather (no float atomics):
//   deg -> dinv -> exclusive scan -> edge fill (CSR by dst) ->
//   hop1: hb(bf16, in d_out) = Ahat @ x ; hop2: h2b(bf16, ws) = Ahat @ hb ->
//   out = h2b @ W + b  (bf16 MFMA 16x16x32).
// Runtime dtype detection: flags[0]=x/W/b are f32 storage, flags[1]=edges int64.
// ws footprint ~33 MB (< 52 MB proven safe in R2).

#define DFEAT 128

typedef __attribute__((ext_vector_type(8))) short short8;
typedef __attribute__((ext_vector_type(4))) float f32x4;

__device__ __forceinline__ float bf2f(unsigned short u) {
    union { unsigned int i; float f; } t;
    t.i = ((unsigned int)u) << 16;
    return t.f;
}

__device__ __forceinline__ unsigned short f2bf(float f) {
    union { float f; unsigned int i; } t;
    t.f = f;
    unsigned int lsb = (t.i >> 16) & 1u;
    t.i += 0x7fffu + lsb;   // round-to-nearest-even
    return (unsigned short)(t.i >> 16);
}

__device__ __forceinline__ int esrc(const int* ei, int e, int i64) {
    return i64 ? ei[2 * e] : ei[e];
}
__device__ __forceinline__ int edst(const int* ei, int e, int E, int i64) {
    return i64 ? ei[2 * (E + e)] : ei[E + e];
}

// ---- dtype detection ----
__global__ void k_detect(const unsigned short* __restrict__ xs,
                         const int* __restrict__ ei, int* __restrict__ flags) {
    __shared__ int s_f32, s_oddnz;
    if (threadIdx.x == 0) { s_f32 = 0; s_oddnz = 0; }
    __syncthreads();
    int bad = 0;
    for (int i = threadIdx.x; i < 16384; i += 256) {
        unsigned int e = (xs[i] >> 7) & 0xFFu;   // bf16 exponent field
        if (e >= 0xC0u) bad = 1;                 // |v| >= 2^65: impossible for real data
    }
    if (bad) atomicOr(&s_f32, 1);
    int oddnz = 0;
    for (int i = threadIdx.x; i < 4096; i += 256) {
        if (ei[2 * i + 1] != 0) oddnz = 1;       // int32 data has nonzero odd words
    }
    if (oddnz) atomicOr(&s_oddnz, 1);
    __syncthreads();
    if (threadIdx.x == 0) {
        flags[0] = s_f32;
        flags[1] = s_oddnz ? 0 : 1;
    }
}

// ---- degree over dst ----
__global__ void k_deg(const int* __restrict__ ei, int E, const int* __restrict__ flags,
                      int* __restrict__ degi) {
    int e = blockIdx.x * 256 + threadIdx.x;
    if (e >= E) return;
    atomicAdd(degi + edst(ei, e, E, flags[1]), 1);
}

__global__ void k_dinv(const int* __restrict__ degi, float* __restrict__ dinv, int n) {
    int i = blockIdx.x * 256 + threadIdx.x;
    if (i < n) dinv[i] = rsqrtf((float)(degi[i] + 1));
}

// ---- 3-kernel exclusive scan of degi -> rowptr ----
__global__ void k_s1(const int* __restrict__ degi, int* __restrict__ bsum, int n) {
    __shared__ int t[256];
    int gid = blockIdx.x * 256 + threadIdx.x;
    t[threadIdx.x] = (gid < n) ? degi[gid] : 0;
    __syncthreads();
    for (int off = 128; off > 0; off >>= 1) {
        if (threadIdx.x < off) t[threadIdx.x] += t[threadIdx.x + off];
        __syncthreads();
    }
    if (threadIdx.x == 0) bsum[blockIdx.x] = t[0];
}

__global__ void k_s2(int* __restrict__ bsum, int nb) {
    __shared__ int t[512];
    int i = threadIdx.x;
    t[i] = (i < nb) ? bsum[i] : 0;
    __syncthreads();
    for (int off = 1; off < 512; off <<= 1) {
        int v = (i >= off) ? t[i - off] : 0;
        __syncthreads();
        t[i] += v;
        __syncthreads();
    }
    if (i < nb) bsum[i] = (i == 0) ? 0 : t[i - 1];   // exclusive
}

__global__ void k_s3(const int* __restrict__ degi, const int* __restrict__ bsum,
                     int* __restrict__ rowptr, int n) {
    __shared__ int t[256];
    int gid = blockIdx.x * 256 + threadIdx.x;
    int v = (gid < n) ? degi[gid] : 0;
    t[threadIdx.x] = v;
    __syncthreads();
    for (int off = 1; off < 256; off <<= 1) {
        int u = (threadIdx.x >= off) ? t[threadIdx.x - off] : 0;
        __syncthreads();
        t[threadIdx.x] += u;
        __syncthreads();
    }
    if (gid < n) rowptr[gid] = bsum[blockIdx.x] + t[threadIdx.x] - v;  // exclusive
}

// ---- CSR fill: rowptr mutates start->end offsets ----
__global__ void k_fill(const int* __restrict__ ei, int E, const int* __restrict__ flags,
                       int* __restrict__ rowptr, int* __restrict__ srcs) {
    int e = blockIdx.x * 256 + threadIdx.x;
    if (e >= E) return;
    int i64 = flags[1];
    int s = esrc(ei, e, i64);
    int d = edst(ei, e, E, i64);
    int pos = atomicAdd(rowptr + d, 1);
    srcs[pos] = s;
}

// ---- hop (pull/gather): out_bf16[dst] = sum_{s in N(dst)} feat[s]*dinv[s]*dinv[dst]
//                                        + feat[dst]*dinv[dst]^2
// One block of 128 threads per dst node; thread owns one feature column.
__global__ __launch_bounds__(128) void k_hop(const void* __restrict__ srcfeat,
                                             const int* __restrict__ srcs,
                                             const int* __restrict__ rowend,
                                             const int* __restrict__ degi,
                                             const float* __restrict__ dinv,
                                             const int* __restrict__ flags, int force_bf16,
                                             unsigned short* __restrict__ outb, int n) {
    int dst = blockIdx.x;
    if (dst >= n) return;
    int tid = threadIdx.x;
    __shared__ int ls[128];
    __shared__ float lw[128];
    int end = rowend[dst];
    int cnt = degi[dst];
    int start = end - cnt;
    float wd = dinv[dst];
    int isf = force_bf16 ? 0 : flags[0];
    const float* ff = (const float*)srcfeat;
    const unsigned short* fb = (const unsigned short*)srcfeat;

    float acc = (isf ? ff[(size_t)dst * DFEAT + tid]
                     : bf2f(fb[(size_t)dst * DFEAT + tid])) * wd * wd;

    for (int base = start; base < end; base += 128) {
        int m = min(128, end - base);
        __syncthreads();
        if (tid < m) {
            int s = srcs[base + tid];
            ls[tid] = s;
            lw[tid] = dinv[s] * wd;
        }
        __syncthreads();
        for (int k = 0; k < m; k++) {
            int s = ls[k];
            float w = lw[k];
            float v = isf ? ff[(size_t)s * DFEAT + tid] : bf2f(fb[(size_t)s * DFEAT + tid]);
            acc += v * w;
        }
    }
    outb[(size_t)dst * DFEAT + tid] = f2bf(acc);
}

// ---- W -> MFMA B-frag linear layout (bf16) ----
__global__ void k_prepB(const void* __restrict__ Wraw, const int* __restrict__ flags,
                        unsigned short* __restrict__ Bf) {
    int t = blockIdx.x * 256 + threadIdx.x;  // 2048 total
    if (t >= 2048) return;
    int lane = t & 63;
    int chunk = (t >> 6) & 3;
    int ntile = t >> 8;
    int ncol = ntile * 16 + (lane & 15);
    int k0 = chunk * 32 + (lane >> 4) * 8;
    int isf = flags[0];
    const float* Wf = (const float*)Wraw;
    const unsigned short* Wb = (const unsigned short*)Wraw;
    unsigned short* o = Bf + (size_t)t * 8;
#pragma unroll
    for (int j = 0; j < 8; j++) {
        int idx = (k0 + j) * DFEAT + ncol;
        o[j] = isf ? f2bf(Wf[idx]) : Wb[idx];
    }
}

// ---- GEMM: out = h2b(bf16) @ W + b, MFMA 16x16x32, one wave per 16-row tile ----
__global__ __launch_bounds__(256) void k_gemm(const unsigned short* __restrict__ h2b,
                                              const unsigned short* __restrict__ Bf,
                                              const void* __restrict__ braw,
                                              const int* __restrict__ flags,
                                              void* __restrict__ outraw, int n) {
    int wave = threadIdx.x >> 6;
    int lane = threadIdx.x & 63;
    int m0 = (blockIdx.x * 4 + wave) * 16;
    if (m0 >= n) return;
    int m = lane & 15, quad = lane >> 4;
    int isf = flags[0];
    const unsigned short* arow = h2b + (size_t)(m0 + m) * DFEAT + quad * 8;

    f32x4 acc[8];
#pragma unroll
    for (int nt = 0; nt < 8; nt++) acc[nt] = (f32x4){0.f, 0.f, 0.f, 0.f};

#pragma unroll
    for (int c = 0; c < 4; c++) {
        short8 af = *(const short8*)(arow + c * 32);   // A[m][k=c*32+quad*8+j]
        const unsigned short* bp = Bf + ((size_t)c * 64 + lane) * 8;
#pragma unroll
        for (int nt = 0; nt < 8; nt++) {
            short8 bfr = *(const short8*)(bp + (size_t)nt * 2048);
            acc[nt] = __builtin_amdgcn_mfma_f32_16x16x32_bf16(af, bfr, acc[nt], 0, 0, 0);
        }
    }

    // C/D layout: col = lane&15, row = quad*4 + reg  [learn_hip m89/m91]
    int row0 = quad * 4;
    const float* bf32 = (const float*)braw;
    const unsigned short* bb16 = (const unsigned short*)braw;
    float* outf = (float*)outraw;
    unsigned short* outb = (unsigned short*)outraw;
#pragma unroll
    for (int nt = 0; nt < 8; nt++) {
        int col = nt * 16 + m;
        float bias = isf ? bf32[col] : bf2f(bb16[col]);
#pragma unroll
        for (int r = 0; r < 4; r++) {
            int row = m0 + row0 + r;
            if (row < n) {
                size_t idx = (size_t)row * DFEAT + col;
                float val = acc[nt][r] + bias;
                if (isf) outf[idx] = val; else outb[idx] = f2bf(val);
            }
        }
    }
}

extern "C" void kernel_launch(void* const* d_in, const int* in_sizes, int n_in,
                              void* d_out, int out_size, void* d_ws, size_t ws_size,
                              hipStream_t stream) {
    const void* x = d_in[0];                 // [n,128] f32 or bf16 (detected)
    const int* ei = (const int*)d_in[1];     // [2,E] int32 or int64 (detected)
    const void* W = d_in[2];                 // [128,128]
    const void* b = d_in[3];                 // [128]

    const int n = in_sizes[0] / DFEAT;       // 100000
    const int E = in_sizes[1] / 2;           // 1600000
    const int NB = (n + 255) / 256;          // 391 scan blocks (<=512)

    // ws layout (16B-aligned pieces):
    // h2b (n*128 bf16, 25.6MB) | srcs (E i32, 6.4MB) | dinv (n f32) | degi (n i32)
    // | rowptr (n i32) | bsum (512 i32) | flags (4 i32) | Bf (16384 bf16)
    unsigned short* h2b = (unsigned short*)d_ws;
    int* srcs = (int*)(h2b + (size_t)n * DFEAT);
    float* dinv = (float*)(srcs + E);
    int* degi = (int*)(dinv + n);
    int* rowptr = degi + n;
    int* bsum = rowptr + n;
    int* flags = bsum + 512;
    unsigned short* Bf = (unsigned short*)(flags + 4);
    unsigned short* hb = (unsigned short*)d_out;   // hop-1 bf16 intermediate in d_out

    hipMemsetAsync(degi, 0, (size_t)n * sizeof(int), stream);

    k_detect<<<1, 256, 0, stream>>>((const unsigned short*)x, ei, flags);
    k_deg<<<(E + 255) / 256, 256, 0, stream>>>(ei, E, flags, degi);
    k_dinv<<<NB, 256, 0, stream>>>(degi, dinv, n);

    // CSR build
    k_s1<<<NB, 256, 0, stream>>>(degi, bsum, n);
    k_s2<<<1, 512, 0, stream>>>(bsum, NB);
    k_s3<<<NB, 256, 0, stream>>>(degi, bsum, rowptr, n);
    k_fill<<<(E + 255) / 256, 256, 0, stream>>>(ei, E, flags, rowptr, srcs);
    // rowptr now holds END offsets; start = end - degi[dst]

    // hop 1: x -> hb (bf16 in d_out)
    k_hop<<<n, 128, 0, stream>>>(x, srcs, rowptr, degi, dinv, flags, /*force_bf16=*/0, hb, n);
    // hop 2: hb -> h2b (bf16 in ws)
    k_hop<<<n, 128, 0, stream>>>(hb, srcs, rowptr, degi, dinv, flags, /*force_bf16=*/1, h2b, n);

    // out = h2b @ W + b
    k_prepB<<<8, 256, 0, stream>>>(W, flags, Bf);
    int mtiles = (n + 15) / 16;                     // 6250
    k_gemm<<<(mtiles + 3) / 4, 256, 0, stream>>>(h2b, Bf, b, flags, d_out, n);
}

// Round 4
// 469.800 us; speedup vs baseline: 11.8449x; 1.3861x over previous
//
#include <hip/hip_runtime.h>
#include <hip/hip_bf16.h>

// GCN 2-hop SGConv via CSR gather (no float atomics):
//   deg -> dinv -> scan -> CSR fill (srcw = {src, dinv[s]*dinv[d]}) ->
//   hop1: hb(bf16, d_out) = Ahat @ x ; hop2: h2b(bf16, ws) = Ahat @ hb ->
//   out = h2b @ W + b (bf16 MFMA 16x16x32).
// Hop = wave-per-node, 16B/lane uint4 loads (16 lanes cover one 256B bf16 row,
// wave processes 4 source rows per load instr, 8 per unrolled trip), shfl-xor
// reduction. Runtime dtype detection: flags[0]=f32 storage, flags[1]=int64 edges.
// ws ~40 MB (< 52 MB proven safe in R2).

#define DFEAT 128

typedef __attribute__((ext_vector_type(8))) short short8;
typedef __attribute__((ext_vector_type(4))) float f32x4;

__device__ __forceinline__ float bf2f(unsigned short u) {
    union { unsigned int i; float f; } t;
    t.i = ((unsigned int)u) << 16;
    return t.f;
}

__device__ __forceinline__ unsigned short f2bf(float f) {
    union { float f; unsigned int i; } t;
    t.f = f;
    unsigned int lsb = (t.i >> 16) & 1u;
    t.i += 0x7fffu + lsb;   // round-to-nearest-even
    return (unsigned short)(t.i >> 16);
}

__device__ __forceinline__ int esrc(const int* ei, int e, int i64) {
    return i64 ? ei[2 * e] : ei[e];
}
__device__ __forceinline__ int edst(const int* ei, int e, int E, int i64) {
    return i64 ? ei[2 * (E + e)] : ei[E + e];
}

// ---- dtype detection ----
__global__ void k_detect(const unsigned short* __restrict__ xs,
                         const int* __restrict__ ei, int* __restrict__ flags) {
    __shared__ int s_f32, s_oddnz;
    if (threadIdx.x == 0) { s_f32 = 0; s_oddnz = 0; }
    __syncthreads();
    int bad = 0;
    for (int i = threadIdx.x; i < 16384; i += 256) {
        unsigned int e = (xs[i] >> 7) & 0xFFu;   // bf16 exponent field
        if (e >= 0xC0u) bad = 1;                 // |v| >= 2^65: impossible for real data
    }
    if (bad) atomicOr(&s_f32, 1);
    int oddnz = 0;
    for (int i = threadIdx.x; i < 4096; i += 256) {
        if (ei[2 * i + 1] != 0) oddnz = 1;       // int32 data has nonzero odd words
    }
    if (oddnz) atomicOr(&s_oddnz, 1);
    __syncthreads();
    if (threadIdx.x == 0) {
        flags[0] = s_f32;
        flags[1] = s_oddnz ? 0 : 1;
    }
}

// ---- degree over dst ----
__global__ void k_deg(const int* __restrict__ ei, int E, const int* __restrict__ flags,
                      int* __restrict__ degi) {
    int e = blockIdx.x * 256 + threadIdx.x;
    if (e >= E) return;
    atomicAdd(degi + edst(ei, e, E, flags[1]), 1);
}

// ---- scan stage 1 (block sums) + dinv fused ----
__global__ void k_s1(const int* __restrict__ degi, int* __restrict__ bsum,
                     float* __restrict__ dinv, int n) {
    __shared__ int t[256];
    int gid = blockIdx.x * 256 + threadIdx.x;
    int v = (gid < n) ? degi[gid] : 0;
    if (gid < n) dinv[gid] = rsqrtf((float)(v + 1));
    t[threadIdx.x] = v;
    __syncthreads();
    for (int off = 128; off > 0; off >>= 1) {
        if (threadIdx.x < off) t[threadIdx.x] += t[threadIdx.x + off];
        __syncthreads();
    }
    if (threadIdx.x == 0) bsum[blockIdx.x] = t[0];
}

__global__ void k_s2(int* __restrict__ bsum, int nb) {
    __shared__ int t[512];
    int i = threadIdx.x;
    t[i] = (i < nb) ? bsum[i] : 0;
    __syncthreads();
    for (int off = 1; off < 512; off <<= 1) {
        int v = (i >= off) ? t[i - off] : 0;
        __syncthreads();
        t[i] += v;
        __syncthreads();
    }
    if (i < nb) bsum[i] = (i == 0) ? 0 : t[i - 1];   // exclusive
}

__global__ void k_s3(const int* __restrict__ degi, const int* __restrict__ bsum,
                     int* __restrict__ rowptr, int n) {
    __shared__ int t[256];
    int gid = blockIdx.x * 256 + threadIdx.x;
    int v = (gid < n) ? degi[gid] : 0;
    t[threadIdx.x] = v;
    __syncthreads();
    for (int off = 1; off < 256; off <<= 1) {
        int u = (threadIdx.x >= off) ? t[threadIdx.x - off] : 0;
        __syncthreads();
        t[threadIdx.x] += u;
        __syncthreads();
    }
    if (gid < n) rowptr[gid] = bsum[blockIdx.x] + t[threadIdx.x] - v;  // exclusive
}

// ---- CSR fill with precomputed edge weights: srcw[pos] = {src, dinv[s]*dinv[d]} ----
__global__ void k_fill(const int* __restrict__ ei, int E, const int* __restrict__ flags,
                       const float* __restrict__ dinv,
                       int* __restrict__ rowptr, int2* __restrict__ srcw) {
    int e = blockIdx.x * 256 + threadIdx.x;
    if (e >= E) return;
    int i64 = flags[1];
    int s = esrc(ei, e, i64);
    int d = edst(ei, e, E, i64);
    int pos = atomicAdd(rowptr + d, 1);
    int2 v; v.x = s; v.y = __float_as_int(dinv[s] * dinv[d]);
    srcw[pos] = v;
}

// ---- hop (pull/gather), wave-per-node ----
// bf16 path: g=lane>>4 in [0,4) picks source slot, c=lane&15 covers 16B of the row.
// f32 path:  g=lane>>5 in [0,2), c=lane&31. Output always bf16.
__global__ __launch_bounds__(256) void k_hop(const void* __restrict__ srcfeat,
                                             const int2* __restrict__ srcw,
                                             const int* __restrict__ rowend,
                                             const int* __restrict__ degi,
                                             const float* __restrict__ dinv,
                                             const int* __restrict__ flags, int force_bf16,
                                             unsigned short* __restrict__ outb, int n) {
    int node = blockIdx.x * 4 + (threadIdx.x >> 6);
    if (node >= n) return;
    int lane = threadIdx.x & 63;
    int end = rowend[node];
    int deg = degi[node];
    int start = end - deg;
    float wd = dinv[node];
    int isf = force_bf16 ? 0 : flags[0];

    if (!isf) {
        const unsigned short* fb = (const unsigned short*)srcfeat;
        int g = lane >> 4, c = lane & 15;
        float acc[8];
#pragma unroll
        for (int j = 0; j < 8; j++) acc[j] = 0.f;

        if (g == 0) {   // self-loop term
            uint4 u = *(const uint4*)(fb + (size_t)node * DFEAT + c * 8);
            float s2 = wd * wd;
            acc[0] = bf2f((unsigned short)(u.x & 0xffffu)) * s2;
            acc[1] = bf2f((unsigned short)(u.x >> 16)) * s2;
            acc[2] = bf2f((unsigned short)(u.y & 0xffffu)) * s2;
            acc[3] = bf2f((unsigned short)(u.y >> 16)) * s2;
            acc[4] = bf2f((unsigned short)(u.z & 0xffffu)) * s2;
            acc[5] = bf2f((unsigned short)(u.z >> 16)) * s2;
            acc[6] = bf2f((unsigned short)(u.w & 0xffffu)) * s2;
            acc[7] = bf2f((unsigned short)(u.w >> 16)) * s2;
        }

        for (int base = 0; base < deg; base += 8) {
            int k0 = base + g, k1 = base + g + 4;
            int2 sw0 = (k0 < deg) ? srcw[start + k0] : make_int2(0, 0);
            int2 sw1 = (k1 < deg) ? srcw[start + k1] : make_int2(0, 0);
            uint4 u0 = *(const uint4*)(fb + (size_t)sw0.x * DFEAT + c * 8);
            uint4 u1 = *(const uint4*)(fb + (size_t)sw1.x * DFEAT + c * 8);
            float w0 = __int_as_float(sw0.y), w1 = __int_as_float(sw1.y);
            acc[0] += bf2f((unsigned short)(u0.x & 0xffffu)) * w0;
            acc[1] += bf2f((unsigned short)(u0.x >> 16)) * w0;
            acc[2] += bf2f((unsigned short)(u0.y & 0xffffu)) * w0;
            acc[3] += bf2f((unsigned short)(u0.y >> 16)) * w0;
            acc[4] += bf2f((unsigned short)(u0.z & 0xffffu)) * w0;
            acc[5] += bf2f((unsigned short)(u0.z >> 16)) * w0;
            acc[6] += bf2f((unsigned short)(u0.w & 0xffffu)) * w0;
            acc[7] += bf2f((unsigned short)(u0.w >> 16)) * w0;
            acc[0] += bf2f((unsigned short)(u1.x & 0xffffu)) * w1;
            acc[1] += bf2f((unsigned short)(u1.x >> 16)) * w1;
            acc[2] += bf2f((unsigned short)(u1.y & 0xffffu)) * w1;
            acc[3] += bf2f((unsigned short)(u1.y >> 16)) * w1;
            acc[4] += bf2f((unsigned short)(u1.z & 0xffffu)) * w1;
            acc[5] += bf2f((unsigned short)(u1.z >> 16)) * w1;
            acc[6] += bf2f((unsigned short)(u1.w & 0xffffu)) * w1;
            acc[7] += bf2f((unsigned short)(u1.w >> 16)) * w1;
        }
#pragma unroll
        for (int j = 0; j < 8; j++) {
            acc[j] += __shfl_xor(acc[j], 16);
            acc[j] += __shfl_xor(acc[j], 32);
        }
        if (g == 0) {
            uint4 o;
            o.x = (unsigned int)f2bf(acc[0]) | ((unsigned int)f2bf(acc[1]) << 16);
            o.y = (unsigned int)f2bf(acc[2]) | ((unsigned int)f2bf(acc[3]) << 16);
            o.z = (unsigned int)f2bf(acc[4]) | ((unsigned int)f2bf(acc[5]) << 16);
            o.w = (unsigned int)f2bf(acc[6]) | ((unsigned int)f2bf(acc[7]) << 16);
            *(uint4*)(outb + (size_t)node * DFEAT + c * 8) = o;
        }
    } else {
        const float* ff = (const float*)srcfeat;
        int g = lane >> 5, c = lane & 31;
        float acc[4];
#pragma unroll
        for (int j = 0; j < 4; j++) acc[j] = 0.f;
        if (g == 0) {
            float4 v = *(const float4*)(ff + (size_t)node * DFEAT + c * 4);
            float s2 = wd * wd;
            acc[0] = v.x * s2; acc[1] = v.y * s2; acc[2] = v.z * s2; acc[3] = v.w * s2;
        }
        for (int base = 0; base < deg; base += 4) {
            int k0 = base + g, k1 = base + g + 2;
            int2 sw0 = (k0 < deg) ? srcw[start + k0] : make_int2(0, 0);
            int2 sw1 = (k1 < deg) ? srcw[start + k1] : make_int2(0, 0);
            float4 v0 = *(const float4*)(ff + (size_t)sw0.x * DFEAT + c * 4);
            float4 v1 = *(const float4*)(ff + (size_t)sw1.x * DFEAT + c * 4);
            float w0 = __int_as_float(sw0.y), w1 = __int_as_float(sw1.y);
            acc[0] += v0.x * w0; acc[1] += v0.y * w0; acc[2] += v0.z * w0; acc[3] += v0.w * w0;
            acc[0] += v1.x * w1; acc[1] += v1.y * w1; acc[2] += v1.z * w1; acc[3] += v1.w * w1;
        }
#pragma unroll
        for (int j = 0; j < 4; j++) acc[j] += __shfl_xor(acc[j], 32);
        if (g == 0) {
            uint2 o;
            o.x = (unsigned int)f2bf(acc[0]) | ((unsigned int)f2bf(acc[1]) << 16);
            o.y = (unsigned int)f2bf(acc[2]) | ((unsigned int)f2bf(acc[3]) << 16);
            *(uint2*)(outb + (size_t)node * DFEAT + c * 4) = o;
        }
    }
}

// ---- W -> MFMA B-frag linear layout (bf16) ----
__global__ void k_prepB(const void* __restrict__ Wraw, const int* __restrict__ flags,
                        unsigned short* __restrict__ Bf) {
    int t = blockIdx.x * 256 + threadIdx.x;  // 2048 total
    if (t >= 2048) return;
    int lane = t & 63;
    int chunk = (t >> 6) & 3;
    int ntile = t >> 8;
    int ncol = ntile * 16 + (lane & 15);
    int k0 = chunk * 32 + (lane >> 4) * 8;
    int isf = flags[0];
    const float* Wf = (const float*)Wraw;
    const unsigned short* Wb = (const unsigned short*)Wraw;
    unsigned short* o = Bf + (size_t)t * 8;
#pragma unroll
    for (int j = 0; j < 8; j++) {
        int idx = (k0 + j) * DFEAT + ncol;
        o[j] = isf ? f2bf(Wf[idx]) : Wb[idx];
    }
}

// ---- GEMM: out = h2b(bf16) @ W + b, MFMA 16x16x32, one wave per 16-row tile ----
__global__ __launch_bounds__(256) void k_gemm(const unsigned short* __restrict__ h2b,
                                              const unsigned short* __restrict__ Bf,
                                              const void* __restrict__ braw,
                                              const int* __restrict__ flags,
                                              void* __restrict__ outraw, int n) {
    int wave = threadIdx.x >> 6;
    int lane = threadIdx.x & 63;
    int m0 = (blockIdx.x * 4 + wave) * 16;
    if (m0 >= n) return;
    int m = lane & 15, quad = lane >> 4;
    int isf = flags[0];
    const unsigned short* arow = h2b + (size_t)(m0 + m) * DFEAT + quad * 8;

    f32x4 acc[8];
#pragma unroll
    for (int nt = 0; nt < 8; nt++) acc[nt] = (f32x4){0.f, 0.f, 0.f, 0.f};

#pragma unroll
    for (int c = 0; c < 4; c++) {
        short8 af = *(const short8*)(arow + c * 32);   // A[m][k=c*32+quad*8+j]
        const unsigned short* bp = Bf + ((size_t)c * 64 + lane) * 8;
#pragma unroll
        for (int nt = 0; nt < 8; nt++) {
            short8 bfr = *(const short8*)(bp + (size_t)nt * 2048);
            acc[nt] = __builtin_amdgcn_mfma_f32_16x16x32_bf16(af, bfr, acc[nt], 0, 0, 0);
        }
    }

    // C/D layout: col = lane&15, row = quad*4 + reg  [learn_hip m89/m91]
    int row0 = quad * 4;
    const float* bf32 = (const float*)braw;
    const unsigned short* bb16 = (const unsigned short*)braw;
    float* outf = (float*)outraw;
    unsigned short* outb = (unsigned short*)outraw;
#pragma unroll
    for (int nt = 0; nt < 8; nt++) {
        int col = nt * 16 + m;
        float bias = isf ? bf32[col] : bf2f(bb16[col]);
#pragma unroll
        for (int r = 0; r < 4; r++) {
            int row = m0 + row0 + r;
            if (row < n) {
                size_t idx = (size_t)row * DFEAT + col;
                float val = acc[nt][r] + bias;
                if (isf) outf[idx] = val; else outb[idx] = f2bf(val);
            }
        }
    }
}

extern "C" void kernel_launch(void* const* d_in, const int* in_sizes, int n_in,
                              void* d_out, int out_size, void* d_ws, size_t ws_size,
                              hipStream_t stream) {
    const void* x = d_in[0];                 // [n,128] f32 or bf16 (detected)
    const int* ei = (const int*)d_in[1];     // [2,E] int32 or int64 (detected)
    const void* W = d_in[2];                 // [128,128]
    const void* b = d_in[3];                 // [128]

    const int n = in_sizes[0] / DFEAT;       // 100000
    const int E = in_sizes[1] / 2;           // 1600000
    const int NB = (n + 255) / 256;          // 391 scan blocks (<=512)

    // ws layout: h2b (n*128 bf16) | srcw (E int2) | dinv (n f32) | degi (n i32)
    // | rowptr (n i32) | bsum (512 i32) | flags (4 i32) | Bf (16384 bf16)  ~= 40 MB
    unsigned short* h2b = (unsigned short*)d_ws;
    int2* srcw = (int2*)(h2b + (size_t)n * DFEAT);
    float* dinv = (float*)(srcw + E);
    int* degi = (int*)(dinv + n);
    int* rowptr = degi + n;
    int* bsum = rowptr + n;
    int* flags = bsum + 512;
    unsigned short* Bf = (unsigned short*)(flags + 4);
    unsigned short* hb = (unsigned short*)d_out;   // hop-1 bf16 intermediate in d_out

    hipMemsetAsync(degi, 0, (size_t)n * sizeof(int), stream);

    k_detect<<<1, 256, 0, stream>>>((const unsigned short*)x, ei, flags);
    k_deg<<<(E + 255) / 256, 256, 0, stream>>>(ei, E, flags, degi);

    // CSR build (+dinv fused into s1)
    k_s1<<<NB, 256, 0, stream>>>(degi, bsum, dinv, n);
    k_s2<<<1, 512, 0, stream>>>(bsum, NB);
    k_s3<<<NB, 256, 0, stream>>>(degi, bsum, rowptr, n);
    k_fill<<<(E + 255) / 256, 256, 0, stream>>>(ei, E, flags, dinv, rowptr, srcw);
    // rowptr now holds END offsets; start = end - degi[dst]

    int hop_blocks = (n + 3) / 4;
    // hop 1: x -> hb (bf16 in d_out)
    k_hop<<<hop_blocks, 256, 0, stream>>>(x, srcw, rowptr, degi, dinv, flags, 0, hb, n);
    // hop 2: hb -> h2b (bf16 in ws)
    k_hop<<<hop_blocks, 256, 0, stream>>>(hb, srcw, rowptr, degi, dinv, flags, 1, h2b, n);

    // out = h2b @ W + b
    k_prepB<<<8, 256, 0, stream>>>(W, flags, Bf);
    int mtiles = (n + 15) / 16;                     // 6250
    k_gemm<<<(mtiles + 3) / 4, 256, 0, stream>>>(h2b, Bf, b, flags, d_out, n);
}